// Round 3
// baseline (863.808 us; speedup 1.0000x reference)
//
#include <hip/hip_runtime.h>

using half8   = __attribute__((ext_vector_type(8))) _Float16;
using floatx4 = __attribute__((ext_vector_type(4))) float;

namespace {
constexpr int S = 196, D = 512, C = 1006, Cpad = 1024;
constexpr int CB   = 16;    // block c-tile
constexpr int EBLK = 256;   // block e-tile (et split; keeps regs at r4 level)
constexpr int BK   = 64;    // k-chunk (8 chunks, 2 MFMA k-steps each)
constexpr int TPB  = 256;   // 4 waves; 3 blocks/CU (reg-limited ~100 VGPR + 64 AGPR)
constexpr int SCH  = 3;     // s-chunks 66/66/64 -> grid 768 = 3 blocks/CU
constexpr int RS   = 64;    // row stride (halfs); 16B-seg XOR swizzle
constexpr float KTANH = 2.885390082f;    // 2/ln2 folded into img staging
constexpr float INVK  = 0.34657359028f;  // ln2/2 to recover raw img
constexpr float LOG2E = 1.44269504f;     // folded into W at prep: acc = log2e*feat

// ws layout (bytes) -- identical to r4 (proven to fit: slice mode ran)
constexpr size_t W16_BYTES   = (size_t)D * D * 2;             // 512 KB swizzled W
constexpr size_t LA_OFF      = W16_BYTES;
constexpr size_t SLICE_ELEMS = (size_t)2 * Cpad * D;
constexpr size_t SL_BYTES    = (size_t)SCH * SLICE_ELEMS * 4; // 12 MB per set
constexpr size_t SLICE_NEED  = LA_OFF + 2 * SL_BYTES;         // ~24.5 MB
constexpr size_t L_BYTES     = SLICE_ELEMS * 4;

// swizzled offset (halfs): row stride 64, 16B-seg XOR'd by row&7.
// Used both for Tc (LDS) and for the global W image (r7: read directly).
__device__ __forceinline__ int sw_off(int row, int seg) {
    return row * RS + ((seg ^ (row & 7)) << 3);
}

__device__ __forceinline__ _Float16 tanh_ps(float y) {
    // y = (2/ln2)*x; tanh(x) = 1 - 2/(exp2(y)+1); saturates correctly
    float e = __builtin_amdgcn_exp2f(y);
    return (_Float16)(1.0f - 2.0f * __builtin_amdgcn_rcpf(e + 1.0f));
}

__device__ __forceinline__ half8 tanh8(floatx4 i0, floatx4 i1, floatx4 w0, floatx4 w1) {
    half8 t;
    t[0] = tanh_ps(i0[0] * w0[0]); t[1] = tanh_ps(i0[1] * w0[1]);
    t[2] = tanh_ps(i0[2] * w0[2]); t[3] = tanh_ps(i0[3] * w0[3]);
    t[4] = tanh_ps(i1[0] * w1[0]); t[5] = tanh_ps(i1[1] * w1[1]);
    t[6] = tanh_ps(i1[2] * w1[2]); t[7] = tanh_ps(i1[3] * w1[3]);
    return t;
}

// Pre-swizzle fc3_w*log2e into the per-chunk image (8 chunks of 512 rows x 8 16B-segs).
__global__ void prep_w16sw(const float* __restrict__ fw, _Float16* __restrict__ W16sw) {
    int id = blockIdx.x * blockDim.x + threadIdx.x;    // 32768 segs
    int kki = id >> 12;
    int r   = (id >> 3) & 511;
    int j   = id & 7;
    const float* src = fw + (size_t)r * D + kki * BK + j * 8;
    floatx4 v0 = *(const floatx4*)src;
    floatx4 v1 = *(const floatx4*)(src + 4);
    half8 h;
    h[0] = (_Float16)(v0[0] * LOG2E); h[1] = (_Float16)(v0[1] * LOG2E);
    h[2] = (_Float16)(v0[2] * LOG2E); h[3] = (_Float16)(v0[3] * LOG2E);
    h[4] = (_Float16)(v1[0] * LOG2E); h[5] = (_Float16)(v1[1] * LOG2E);
    h[6] = (_Float16)(v1[2] * LOG2E); h[7] = (_Float16)(v1[3] * LOG2E);
    *(half8*)&W16sw[((size_t)kki << 15) + r * RS + ((j ^ (r & 7)) << 3)] = h;
}

// r7 = r4 skeleton (4 waves, 3 blocks/CU, et split) with:
//  - W LDS staging DELETED: bf frags read directly from the L2-resident
//    swizzled image (same bytes; 16 rows x full 64B line per instr = coalesced).
//    Removes r4's ~90us of single-buffered DMA drain.
//  - Tc double-buffered: tanh(chunk k+1) runs between chunk k's two MFMA
//    half-steps; one barrier per chunk (r4 had two).
__global__ __launch_bounds__(TPB, 3) void semdec_mfma(
    const float* __restrict__ img, const float* __restrict__ word,
    const _Float16* __restrict__ W16sw,
    float* __restrict__ lbase, float* __restrict__ abase, int use_slice)
{
    __shared__ __align__(16) _Float16 Tc[2][4 * CB * RS]; // 2 x 8 KB
    __shared__ __align__(16) float imgS[4][D];            // 8 KB, pre-scaled by 2/ln2
    // total 24 KB

    const int ct = blockIdx.x;           // 0..63
    const int et = blockIdx.y & 1;       // 0..1
    const int b  = blockIdx.y >> 1;      // 0..1
    const int sc = blockIdx.z;           // 0..2

    const int tid  = threadIdx.x;
    const int lane = tid & 63;
    const int wv   = tid >> 6;           // wave 0..3 = 64-wide e-slot
    const int l15  = lane & 15;
    const int quad = lane >> 4;

    const int c0 = ct * CB;
    const int e0 = et * EBLK;

    // T-stage mapping (r4): thread -> fixed (ciT, segT); si = it*2 + siB
    const int siB  = tid >> 7;           // 0..1
    const int ciT  = (tid & 127) >> 3;   // 0..15
    const int segT = tid & 7;
    int cgT = c0 + ciT; if (cgT > C - 1) cgT = C - 1;   // clamp pad rows
    const float* wordRowT = word + (size_t)cgT * D + segT * 8;

    floatx4 lacc[4], aacc[4];            // 32 VGPR softmax sums
    #pragma unroll
    for (int ej = 0; ej < 4; ++ej) {
        lacc[ej] = (floatx4){0.f, 0.f, 0.f, 0.f};
        aacc[ej] = (floatx4){0.f, 0.f, 0.f, 0.f};
    }

    const float* imgB = img + (size_t)b * S * D;
    const int s_base = sc * 66;                       // 0, 66, 132
    const int npass = (sc < 2) ? 17 : 16;             // 16x4s (+1x2s for sc<2)

    // cyclic word prefetch: wc = word chunk for NEXT T compute; wn = one further
    floatx4 wc0 = *(const floatx4*)(wordRowT);
    floatx4 wc1 = *(const floatx4*)(wordRowT + 4);
    floatx4 wn0 = *(const floatx4*)(wordRowT + BK);
    floatx4 wn1 = *(const floatx4*)(wordRowT + BK + 4);

    for (int pr = 0; pr < npass; ++pr) {
        const int s0 = s_base + pr * 4;
        const int slim = (pr == 16) ? 2 : 4;          // tail pass covers 2 s

        __syncthreads();  // prior pass epilogue done reading imgS; Tc free
        #pragma unroll
        for (int it = 0; it < 2; ++it) {
            int sid = it * TPB + tid;
            int si = sid >> 7, pos = (sid & 127) << 2;
            floatx4 v = *(const floatx4*)&imgB[(size_t)(s0 + si) * D + pos];
            floatx4 sv = {v[0] * KTANH, v[1] * KTANH, v[2] * KTANH, v[3] * KTANH};
            *(floatx4*)&imgS[si][pos] = sv;
        }
        __syncthreads();  // imgS visible

        // pass prologue: T(chunk 0) -> Tc[0]  (wc holds word chunk 0)
        #pragma unroll
        for (int it = 0; it < 2; ++it) {
            int si = it * 2 + siB;
            const float* ip = &imgS[si][segT * 8];
            floatx4 i0 = *(const floatx4*)ip;
            floatx4 i1 = *(const floatx4*)(ip + 4);
            *(half8*)&Tc[0][sw_off(si * CB + ciT, segT)] = tanh8(i0, i1, wc0, wc1);
        }
        wc0 = wn0; wc1 = wn1;  // wc <- word chunk 1

        floatx4 acc[4][4];   // [si][ej] 64 AGPR
        #pragma unroll
        for (int si = 0; si < 4; ++si)
            #pragma unroll
            for (int ej = 0; ej < 4; ++ej)
                acc[si][ej] = (floatx4){0.f, 0.f, 0.f, 0.f};

        for (int kk = 0; kk < 8; ++kk) {
            const int p = kk & 1;
            __syncthreads();  // Tc[p] (written last iter / prologue) visible;
                              // prev readers of Tc[p^1] done

            // word prefetch for chunk (kk+2)&7 (cyclic across the pass boundary:
            // kk=6 loads next pass's chunk 0, kk=7 loads its chunk 1)
            {
                const int kc = ((kk + 2) & 7) * BK;
                wn0 = *(const floatx4*)(wordRowT + kc);
                wn1 = *(const floatx4*)(wordRowT + kc + 4);
            }

            const _Float16* wgk = W16sw + ((size_t)kk << 15);

            // --- k2=0: bf direct from global W image + af from Tc[p] + 16 MFMA
            {
                half8 bf[4], af[4];
                #pragma unroll
                for (int ej = 0; ej < 4; ++ej)
                    bf[ej] = *(const half8*)&wgk[sw_off(e0 + wv * 64 + ej * 16 + l15, quad)];
                #pragma unroll
                for (int si = 0; si < 4; ++si)
                    af[si] = *(const half8*)&Tc[p][sw_off(si * CB + l15, quad)];
                #pragma unroll
                for (int si = 0; si < 4; ++si)
                    #pragma unroll
                    for (int ej = 0; ej < 4; ++ej)
                        acc[si][ej] = __builtin_amdgcn_mfma_f32_16x16x32_f16(
                            af[si], bf[ej], acc[si][ej], 0, 0, 0);
            }

            // --- k2=1 bf loads issued early (latency hides under the tanh below)
            half8 bf1[4];
            #pragma unroll
            for (int ej = 0; ej < 4; ++ej)
                bf1[ej] = *(const half8*)&wgk[sw_off(e0 + wv * 64 + ej * 16 + l15, 4 + quad)];

            // --- pipelined T(kk+1) -> Tc[p^1]; VALU/trans overlaps matrix pipe
            if (kk < 7) {
                #pragma unroll
                for (int it = 0; it < 2; ++it) {
                    int si = it * 2 + siB;
                    const float* ip = &imgS[si][((kk + 1) << 6) + segT * 8];
                    floatx4 i0 = *(const floatx4*)ip;
                    floatx4 i1 = *(const floatx4*)(ip + 4);
                    *(half8*)&Tc[p ^ 1][sw_off(si * CB + ciT, segT)] = tanh8(i0, i1, wc0, wc1);
                }
                wc0 = wn0; wc1 = wn1;
            }

            // --- k2=1: af from Tc[p] + 16 MFMA
            {
                half8 af[4];
                #pragma unroll
                for (int si = 0; si < 4; ++si)
                    af[si] = *(const half8*)&Tc[p][sw_off(si * CB + l15, 4 + quad)];
                #pragma unroll
                for (int si = 0; si < 4; ++si)
                    #pragma unroll
                    for (int ej = 0; ej < 4; ++ej)
                        acc[si][ej] = __builtin_amdgcn_mfma_f32_16x16x32_f16(
                            af[si], bf1[ej], acc[si][ej], 0, 0, 0);
            }
        }

        // --- online softmax accumulate; acc = log2e*feat so exp2(acc) = exp(feat)
        #pragma unroll
        for (int si = 0; si < 4; ++si) {
            if (si >= slim) break;
            #pragma unroll
            for (int ej = 0; ej < 4; ++ej) {
                float ie = imgS[si][e0 + wv * 64 + ej * 16 + l15] * INVK;
                #pragma unroll
                for (int r = 0; r < 4; ++r) {
                    float ev = __builtin_amdgcn_exp2f(acc[si][ej][r]);
                    lacc[ej][r] += ev;
                    aacc[ej][r] += ie * ev;
                }
            }
        }
    }

    // --- writeout (C/D layout: col=lane&15 -> e, row=quad*4+r -> c)
    if (use_slice) {
        float* lsl = lbase + (size_t)sc * SLICE_ELEMS;
        float* asl = abase + (size_t)sc * SLICE_ELEMS;
        #pragma unroll
        for (int r = 0; r < 4; ++r) {
            int cg = c0 + quad * 4 + r;
            #pragma unroll
            for (int ej = 0; ej < 4; ++ej) {
                int eg = e0 + wv * 64 + ej * 16 + l15;
                size_t o = ((size_t)b * Cpad + cg) * D + eg;
                lsl[o] = lacc[ej][r];
                asl[o] = aacc[ej][r];
            }
        }
    } else {
        #pragma unroll
        for (int r = 0; r < 4; ++r) {
            int cg = c0 + quad * 4 + r;
            #pragma unroll
            for (int ej = 0; ej < 4; ++ej) {
                int eg = e0 + wv * 64 + ej * 16 + l15;
                atomicAdd(&lbase[((size_t)b * Cpad + cg) * D + eg], lacc[ej][r]);
                if (cg < C)
                    atomicAdd(&abase[((size_t)b * C + cg) * D + eg], aacc[ej][r]);
            }
        }
    }
}

__global__ void finalize_k(const float* __restrict__ lbase, const float* __restrict__ abase,
                           float* __restrict__ out, int use_slice) {
    int o = blockIdx.x * blockDim.x + threadIdx.x;
    if (o >= 2 * C * D) return;
    int b = o / (C * D);
    int rem = o - b * (C * D);
    int c = rem >> 9;
    int e = rem & (D - 1);
    size_t p = ((size_t)b * Cpad + c) * D + e;
    if (use_slice) {
        float l = 0.f, a = 0.f;
        #pragma unroll
        for (int scn = 0; scn < SCH; ++scn) {
            l += lbase[(size_t)scn * SLICE_ELEMS + p];
            a += abase[(size_t)scn * SLICE_ELEMS + p];
        }
        out[o] = a / l;
    } else {
        out[o] = out[o] / lbase[p];
    }
}

} // namespace

extern "C" void kernel_launch(void* const* d_in, const int* in_sizes, int n_in,
                              void* d_out, int out_size, void* d_ws, size_t ws_size,
                              hipStream_t stream) {
    const float* img  = (const float*)d_in[0];
    const float* word = (const float*)d_in[1];
    const float* fw   = (const float*)d_in[2];
    // d_in[3] = fc3_b: constant over softmax axis s -> cancels exactly.
    float* out = (float*)d_out;
    char* ws = (char*)d_ws;

    _Float16* W16sw = (_Float16*)ws;
    const int use_slice = (ws_size >= SLICE_NEED) ? 1 : 0;

    hipLaunchKernelGGL(prep_w16sw, dim3(128), dim3(256), 0, stream, fw, W16sw);

    float *lbase, *abase;
    if (use_slice) {
        lbase = (float*)(ws + LA_OFF);
        abase = (float*)(ws + LA_OFF + SL_BYTES);
    } else {
        lbase = (float*)(ws + LA_OFF);
        abase = out;
        hipMemsetAsync(lbase, 0, L_BYTES, stream);
        hipMemsetAsync(out, 0, (size_t)2 * C * D * 4, stream);
    }

    hipLaunchKernelGGL(semdec_mfma, dim3(64, 4, SCH), dim3(TPB), 0, stream,
                       img, word, W16sw, lbase, abase, use_slice);

    hipLaunchKernelGGL(finalize_k, dim3((2 * C * D + 255) / 256), dim3(256), 0, stream,
                       lbase, abase, out, use_slice);
}

// Round 4
// 326.724 us; speedup vs baseline: 2.6438x; 2.6438x over previous
//
#include <hip/hip_runtime.h>

using half8   = __attribute__((ext_vector_type(8))) _Float16;
using floatx4 = __attribute__((ext_vector_type(4))) float;

namespace {
constexpr int S = 196, D = 512, C = 1006;
constexpr int CB   = 16;    // block c-tile
constexpr int EBLK = 256;   // block e-tile (et split; keeps VGPR sane, known 2x tanh cost)
constexpr int BK   = 64;    // k-chunk (8 chunks, 2 MFMA k-steps each)
constexpr int TPB  = 512;   // 8 waves = 4 e-slots x 2 s-groups; grid 256 = 1 block/CU
constexpr int RS   = 64;    // row stride (halfs); 16B-seg XOR swizzle
constexpr float KTANH = 2.885390082f;    // 2/ln2 folded into img staging
constexpr float INVK  = 0.34657359028f;  // ln2/2 to recover raw img
constexpr float LOG2E = 1.44269504f;     // folded into W at prep: acc = log2e*feat

// r8: NO slice workspace, NO atomics, NO finalize kernel. The only ws use is the
// 512 KB swizzled W image (every prior round proved ws >= ~4.5 MB). This removes
// the ws_size-dependent atomic fallback that poisoned r5/r6/r7 (394 MB atomic
// line-RMW writes + L2 thrash -> 2 GB FETCH).

// swizzled offset (halfs): row stride 64, 16B-seg XOR'd by row&7
// (conflict-free b128 frag reads: SQ_LDS_BANK_CONFLICT == 0 in r4)
__device__ __forceinline__ int sw_off(int row, int seg) {
    return row * RS + ((seg ^ (row & 7)) << 3);
}

__device__ __forceinline__ void gload16(const _Float16* g, _Float16* l) {
    // async global->LDS, 16B/lane; LDS dest = wave-uniform base + lane*16
    __builtin_amdgcn_global_load_lds(
        (const __attribute__((address_space(1))) unsigned int*)g,
        (__attribute__((address_space(3))) unsigned int*)l, 16, 0, 0);
}

__device__ __forceinline__ _Float16 tanh_ps(float y) {
    // y = (2/ln2)*x; tanh(x) = 1 - 2/(exp2(y)+1); saturates correctly
    float e = __builtin_amdgcn_exp2f(y);
    return (_Float16)(1.0f - 2.0f * __builtin_amdgcn_rcpf(e + 1.0f));
}

__device__ __forceinline__ half8 tanh8(floatx4 i0, floatx4 i1, floatx4 w0, floatx4 w1) {
    half8 t;
    t[0] = tanh_ps(i0[0] * w0[0]); t[1] = tanh_ps(i0[1] * w0[1]);
    t[2] = tanh_ps(i0[2] * w0[2]); t[3] = tanh_ps(i0[3] * w0[3]);
    t[4] = tanh_ps(i1[0] * w1[0]); t[5] = tanh_ps(i1[1] * w1[1]);
    t[6] = tanh_ps(i1[2] * w1[2]); t[7] = tanh_ps(i1[3] * w1[3]);
    return t;
}

// Pre-swizzle fc3_w*log2e into the per-chunk image (8 chunks of 512 rows x 8 16B-segs)
// -- exactly the LDS image the main kernel DMAs per chunk (et blocks take a 32 KB half).
__global__ void prep_w16sw(const float* __restrict__ fw, _Float16* __restrict__ W16sw) {
    int id = blockIdx.x * blockDim.x + threadIdx.x;    // 32768 segs
    int kki = id >> 12;
    int r   = (id >> 3) & 511;
    int j   = id & 7;
    const float* src = fw + (size_t)r * D + kki * BK + j * 8;
    floatx4 v0 = *(const floatx4*)src;
    floatx4 v1 = *(const floatx4*)(src + 4);
    half8 h;
    h[0] = (_Float16)(v0[0] * LOG2E); h[1] = (_Float16)(v0[1] * LOG2E);
    h[2] = (_Float16)(v0[2] * LOG2E); h[3] = (_Float16)(v0[3] * LOG2E);
    h[4] = (_Float16)(v1[0] * LOG2E); h[5] = (_Float16)(v1[1] * LOG2E);
    h[6] = (_Float16)(v1[2] * LOG2E); h[7] = (_Float16)(v1[3] * LOG2E);
    *(half8*)&W16sw[((size_t)kki << 15) + r * RS + ((j ^ (r & 7)) << 3)] = h;
}

// One block = (b, 16-c tile, 256-e half) over ALL 196 s-rows: full softmax local.
// 8 waves: wv&3 = e-slot, wv>>2 = s-group (4 s-rows each of the 8-row pass).
// W double-buffered via global_load_lds (DMA of chunk k+1 issued after chunk k's
// barrier -> drains one full chunk later, covered by tanh+32 MFMA).
__global__ __launch_bounds__(TPB, 2) void semdec_mfma(
    const float* __restrict__ img, const float* __restrict__ word,
    const _Float16* __restrict__ W16sw, float* __restrict__ out)
{
    __shared__ __align__(16) _Float16 Wc[2][EBLK * RS];     // 2 x 32 KB
    __shared__ __align__(16) _Float16 Tc[2][8 * CB * RS];   // 2 x 16 KB (8s x 16c x 64k)
    __shared__ __align__(16) float imgS[8][D];              // 16 KB, pre-scaled by 2/ln2
    // total 112 KB -> 1 block/CU (grid 256 = #CUs)

    const int ct = blockIdx.x;           // 0..63
    const int b  = blockIdx.y;           // 0..1
    const int et = blockIdx.z;           // 0..1

    const int tid  = threadIdx.x;
    const int lane = tid & 63;
    const int wv   = tid >> 6;           // 0..7
    const int l15  = lane & 15;
    const int quad = lane >> 4;
    const int sg   = wv >> 2;            // s-group 0/1
    const int ew   = wv & 3;             // e-slot 0..3 (64-wide)

    const int c0 = ct * CB;
    const int e0 = et * EBLK;

    // T-stage mapping: thread -> (sT2, ciT, segT); s_localT = it*4 + sT2
    const int sT2  = tid >> 7;           // 0..3
    const int ciT  = (tid >> 3) & 15;
    const int segT = tid & 7;
    int cgT = c0 + ciT; if (cgT > C - 1) cgT = C - 1;   // clamp pad rows
    const float* wordRowT = word + (size_t)cgT * D + segT * 8;

    floatx4 lacc[4], aacc[4];            // per-thread softmax sums (this sg's s-subset)
    #pragma unroll
    for (int ej = 0; ej < 4; ++ej) {
        lacc[ej] = (floatx4){0.f, 0.f, 0.f, 0.f};
        aacc[ej] = (floatx4){0.f, 0.f, 0.f, 0.f};
    }

    const float* imgB = img + (size_t)b * S * D;
    constexpr int NPASS = 25;            // 24 x 8s + 1 x 4s = 196

    // cyclic word prefetch: wc = chunk for NEXT T compute; wn = one further
    floatx4 wc0 = *(const floatx4*)(wordRowT);
    floatx4 wc1 = *(const floatx4*)(wordRowT + 4);
    floatx4 wn0 = *(const floatx4*)(wordRowT + BK);
    floatx4 wn1 = *(const floatx4*)(wordRowT + BK + 4);

    // prime: DMA chunk 0 -> Wc[0] (later passes get it from chunk 7's in-body issue)
    {
        const _Float16* wg = W16sw + ((size_t)e0 << 6);
        #pragma unroll
        for (int it = 0; it < 4; ++it) {
            int o = ((wv * 4 + it) << 9) + (lane << 3);
            gload16(wg + o, &Wc[0][o]);
        }
    }

    for (int pr = 0; pr < NPASS; ++pr) {
        const int s0 = pr * 8;
        const int slim = (pr == NPASS - 1) ? 4 : 8;

        __syncthreads();  // prev pass readers of imgS done
        #pragma unroll
        for (int it = 0; it < 2; ++it) {
            int idx = it * TPB + tid;
            int row = idx >> 7, pos = (idx & 127) << 2;
            int srow = s0 + row; if (srow > S - 1) srow = S - 1;  // tail clamp
            floatx4 v = *(const floatx4*)&imgB[(size_t)srow * D + pos];
            floatx4 sv = {v[0] * KTANH, v[1] * KTANH, v[2] * KTANH, v[3] * KTANH};
            *(floatx4*)&imgS[row][pos] = sv;
        }
        __syncthreads();  // imgS visible

        // pass prologue: T(chunk 0) -> Tc[0] (wc holds word chunk 0)
        #pragma unroll
        for (int it = 0; it < 2; ++it) {
            int sl = it * 4 + sT2;
            const float* ip = &imgS[sl][segT * 8];
            floatx4 i0 = *(const floatx4*)ip;
            floatx4 i1 = *(const floatx4*)(ip + 4);
            *(half8*)&Tc[0][sw_off(sl * CB + ciT, segT)] = tanh8(i0, i1, wc0, wc1);
        }
        wc0 = wn0; wc1 = wn1;  // wc <- word chunk 1

        floatx4 acc[4][4];   // [si][ej]; si = this sg's 4 s-rows
        #pragma unroll
        for (int si = 0; si < 4; ++si)
            #pragma unroll
            for (int ej = 0; ej < 4; ++ej)
                acc[si][ej] = (floatx4){0.f, 0.f, 0.f, 0.f};

        for (int kk = 0; kk < 8; ++kk) {
            const int p = kk & 1;
            __syncthreads();  // Wc[p] DMA drained; Tc[p] visible; [p^1] readers done

            // --- issue DMA of W chunk (kk+1)&7 -> Wc[p^1]; drains at NEXT chunk's
            //     barrier, covered by this chunk's tanh + 32 MFMA. kk==7 -> next
            //     pass's chunk 0 (cyclic W image, address identical every pass).
            {
                const _Float16* wg = W16sw + ((size_t)((kk + 1) & 7) << 15) + ((size_t)e0 << 6);
                #pragma unroll
                for (int it = 0; it < 4; ++it) {
                    int o = ((wv * 4 + it) << 9) + (lane << 3);
                    gload16(wg + o, &Wc[p ^ 1][o]);
                }
            }

            // --- word prefetch for chunk (kk+2)&7 (cyclic across pass boundary)
            {
                const int kc = ((kk + 2) & 7) * BK;
                wn0 = *(const floatx4*)(wordRowT + kc);
                wn1 = *(const floatx4*)(wordRowT + kc + 4);
            }

            // --- k2=0: frags + 16 MFMA (only bf[4]+af[4] live -> no spill)
            {
                half8 bf[4], af[4];
                #pragma unroll
                for (int ej = 0; ej < 4; ++ej)
                    bf[ej] = *(const half8*)&Wc[p][sw_off(ew * 64 + ej * 16 + l15, quad)];
                #pragma unroll
                for (int si = 0; si < 4; ++si)
                    af[si] = *(const half8*)&Tc[p][sw_off((sg * 4 + si) * CB + l15, quad)];
                #pragma unroll
                for (int si = 0; si < 4; ++si)
                    #pragma unroll
                    for (int ej = 0; ej < 4; ++ej)
                        acc[si][ej] = __builtin_amdgcn_mfma_f32_16x16x32_f16(
                            af[si], bf[ej], acc[si][ej], 0, 0, 0);
            }

            // --- pipelined T(kk+1) -> Tc[p^1]; VALU/trans overlaps matrix pipe
            if (kk < 7) {
                #pragma unroll
                for (int it = 0; it < 2; ++it) {
                    int sl = it * 4 + sT2;
                    const float* ip = &imgS[sl][((kk + 1) << 6) + segT * 8];
                    floatx4 i0 = *(const floatx4*)ip;
                    floatx4 i1 = *(const floatx4*)(ip + 4);
                    *(half8*)&Tc[p ^ 1][sw_off(sl * CB + ciT, segT)] = tanh8(i0, i1, wc0, wc1);
                }
                wc0 = wn0; wc1 = wn1;
            }

            // --- k2=1: frags + 16 MFMA
            {
                half8 bf[4], af[4];
                #pragma unroll
                for (int ej = 0; ej < 4; ++ej)
                    bf[ej] = *(const half8*)&Wc[p][sw_off(ew * 64 + ej * 16 + l15, 4 + quad)];
                #pragma unroll
                for (int si = 0; si < 4; ++si)
                    af[si] = *(const half8*)&Tc[p][sw_off((sg * 4 + si) * CB + l15, 4 + quad)];
                #pragma unroll
                for (int si = 0; si < 4; ++si)
                    #pragma unroll
                    for (int ej = 0; ej < 4; ++ej)
                        acc[si][ej] = __builtin_amdgcn_mfma_f32_16x16x32_f16(
                            af[si], bf[ej], acc[si][ej], 0, 0, 0);
            }
        }

        // --- online softmax accumulate; acc = log2e*feat so exp2(acc) = exp(feat)
        #pragma unroll
        for (int si = 0; si < 4; ++si) {
            const int sl = sg * 4 + si;
            if (sl >= slim) break;    // tail pass: sg=1 contributes nothing
            #pragma unroll
            for (int ej = 0; ej < 4; ++ej) {
                float ie = imgS[sl][e0 + ew * 64 + ej * 16 + l15] * INVK;
                #pragma unroll
                for (int r = 0; r < 4; ++r) {
                    float ev = __builtin_amdgcn_exp2f(acc[si][ej][r]);
                    lacc[ej][r] += ev;
                    aacc[ej][r] += ie * ev;
                }
            }
        }
    }

    // --- combine the two s-groups (LDS, one-time) and write final a/l to out
    __syncthreads();
    float* red = (float*)&Wc[0][0];      // reuse 32 KB of Wc
    if (sg == 1) {
        const int base = (tid - 256) * 32;
        #pragma unroll
        for (int ej = 0; ej < 4; ++ej)
            #pragma unroll
            for (int r = 0; r < 4; ++r) {
                red[base + ej * 8 + r * 2]     = lacc[ej][r];
                red[base + ej * 8 + r * 2 + 1] = aacc[ej][r];
            }
    }
    __syncthreads();
    if (sg == 0) {
        const int base = tid * 32;
        #pragma unroll
        for (int r = 0; r < 4; ++r) {
            const int cg = c0 + quad * 4 + r;
            if (cg < C) {
                #pragma unroll
                for (int ej = 0; ej < 4; ++ej) {
                    float l = lacc[ej][r] + red[base + ej * 8 + r * 2];
                    float a = aacc[ej][r] + red[base + ej * 8 + r * 2 + 1];
                    const int eg = e0 + ew * 64 + ej * 16 + l15;
                    out[((size_t)b * C + cg) * D + eg] = a / l;
                }
            }
        }
    }
}

} // namespace

extern "C" void kernel_launch(void* const* d_in, const int* in_sizes, int n_in,
                              void* d_out, int out_size, void* d_ws, size_t ws_size,
                              hipStream_t stream) {
    const float* img  = (const float*)d_in[0];
    const float* word = (const float*)d_in[1];
    const float* fw   = (const float*)d_in[2];
    // d_in[3] = fc3_b: constant over softmax axis s -> cancels exactly.
    float* out = (float*)d_out;

    _Float16* W16sw = (_Float16*)d_ws;   // 512 KB; only workspace use

    hipLaunchKernelGGL(prep_w16sw, dim3(128), dim3(256), 0, stream, fw, W16sw);
    hipLaunchKernelGGL(semdec_mfma, dim3(64, 2, 2), dim3(TPB), 0, stream,
                       img, word, W16sw, out);
}